// Round 6
// baseline (552.039 us; speedup 1.0000x reference)
//
#include <hip/hip_runtime.h>

// Problem constants (fixed by setup_inputs)
#define B_   4
#define C_   256
#define H_   96
#define W_   128
#define F_   9
#define G_   4
#define CG   64            // channels per group
#define NC4  16            // channel QUADS per group
#define NO   81            // offsets
#define TH   2             // output rows per block
#define TCOLS (W_ + 16)    // 144 cols incl halo (even -> pixel pairs never straddle rows)
#define HW_  (H_ * W_)

// Per-pass geometry: 3 dy-values per pass (dy = pass*3 + dyp)
#define NDY   3
#define PROWS (2 * NDY)          // 6 tile rows per pass (dilation=2, TH=2)
#define PTE   (PROWS * TCOLS)    // 864 pixels, 8B each (4 ch f16)
#define NPCH  2                  // pair-chunks: 512 + 352 pixels

typedef _Float16 half2v __attribute__((ext_vector_type(2)));
typedef unsigned u32x2 __attribute__((ext_vector_type(2)));
typedef unsigned u32x4 __attribute__((ext_vector_type(4)));
typedef float    f32x2 __attribute__((ext_vector_type(2)));

__device__ __forceinline__ half2v u2h(unsigned u) {
    half2v h; __builtin_memcpy(&h, &u, 4); return h;
}
__device__ __forceinline__ unsigned h2u(half2v h) {
    unsigned u; __builtin_memcpy(&u, &h, 4); return u;
}
__device__ __forceinline__ half2v pkrtz(float a, float b) {
    auto r = __builtin_amdgcn_cvt_pkrtz(a, b);
    half2v h; __builtin_memcpy(&h, &r, 4); return h;
}
__device__ __forceinline__ unsigned pkrtz_u(float a, float b) {
    auto r = __builtin_amdgcn_cvt_pkrtz(a, b);
    unsigned u; __builtin_memcpy(&u, &r, 4); return u;
}

#if __has_builtin(__builtin_amdgcn_fdot2)
#define FDOT2(a, b, c) __builtin_amdgcn_fdot2((a), (b), (c), false)
#else
__device__ __forceinline__ float fdot2_fb(half2v a, half2v b, float c) {
    return c + (float)a[0] * (float)b[0] + (float)a[1] * (float)b[1];
}
#define FDOT2(a, b, c) fdot2_fb((a), (b), (c))
#endif

// Pack weights [C,9,9] f32 -> [g][c4][o] as 4-channel (2x f16x2) in d_ws
__global__ void pack_weights_kernel(const float* __restrict__ w,
                                    u32x2* __restrict__ wp) {
    int i = blockIdx.x * blockDim.x + threadIdx.x;
    if (i >= G_ * NC4 * NO) return;
    int o  = i % NO;
    int c4 = (i / NO) % NC4;
    int g  = i / (NO * NC4);
    const float* base = w + (size_t)(g * CG + 4 * c4) * NO + o;
    u32x2 r;
    r.x = pkrtz_u(base[0], base[NO]);
    r.y = pkrtz_u(base[2 * NO], base[3 * NO]);
    wp[i] = r;
}

template <bool PACKED>
__global__ __launch_bounds__(256)
void wcorr_kernel(const float* __restrict__ in1, const float* __restrict__ in2,
                  const u32x2* __restrict__ wp, const float* __restrict__ wraw,
                  float* __restrict__ out) {
    __shared__ u32x2 tile[2][PTE];   // 13,824 B total

    // grid = 16 pairs x 3 passes x 48 hblks = 2304 blocks
    // XCD-aware: (b,g) pair constant per XCD run -> in2 plane stays in XCD L2
    int bid  = blockIdx.x;
    int xcd  = bid & 7;
    int slot = bid >> 3;                 // 0..287
    int pair = xcd + 8 * (slot / 144);   // 0..15  == b*4+g
    int rem  = slot % 144;
    int pass = rem / 48;                 // 0..2  (dy block)
    int hblk = rem % 48;
    int b = pair >> 2, g = pair & 3;
    int h0 = hblk * TH;

    int t  = threadIdx.x;
    int ty = t >> 7;                // 0..1
    int tx = t & 127;               // 0..127

    const float* in1g = in1 + (size_t)(b * C_ + g * CG) * HW_;
    const float* in2g = in2 + (size_t)(b * C_ + g * CG) * HW_;

    // ---- pair-pixel staging geometry (c4-invariant) ----
    // Each thread stages 2 adjacent pixels per chunk; pairs never straddle a
    // tile row (TCOLS even) so one clamp+mask covers both.
    const int gr0 = h0 - 8 + 6 * pass;
    int ppo[NPCH];       // clamped byte-safe element offset of the pair
    unsigned pmm[NPCH];  // f16x2 (m,m) zero-mask
#pragma unroll
    for (int c = 0; c < NPCH; ++c) {
        int pidx = c * 512 + 2 * t;
        int row = pidx / TCOLS;
        int col = pidx - row * TCOLS;
        int gr = gr0 + row, gc = col - 8;
        bool inb = (pidx < PTE) && gr >= 0 && gr < H_ && gc >= 0 && gc < (W_ - 1);
        int off = gr * W_ + gc;
        off = off < 0 ? 0 : (off > HW_ - 2 ? HW_ - 2 : off);
        ppo[c] = off;
        float m = inb ? 1.f : 0.f;
        pmm[c] = pkrtz_u(m, m);
    }

    float acc[NDY * F_];
#pragma unroll
    for (int o = 0; o < NDY * F_; ++o) acc[o] = 0.f;

    f32x2 xs[NPCH][4];   // staged pair per channel (in flight)

    auto STAGE_LOAD = [&](int c4n) {
        const float* chb = in2g + (size_t)(4 * c4n) * HW_;
#pragma unroll
        for (int c = 0; c < NPCH; ++c)
#pragma unroll
            for (int q = 0; q < 4; ++q)
                xs[c][q] = *(const f32x2*)(chb + (size_t)q * HW_ + ppo[c]);
    };
    auto STAGE_WRITE = [&](u32x2* dst) {
#pragma unroll
        for (int c = 0; c < NPCH; ++c) {
            int pidx = c * 512 + 2 * t;
            if (c == 0 || t < (PTE - 512) / 2) {   // chunk1: 176 active threads
                half2v mm = u2h(pmm[c]);
                half2v pa0 = u2h(pkrtz_u(xs[c][0].x, xs[c][1].x)) * mm; // pix A ch01
                half2v pa1 = u2h(pkrtz_u(xs[c][2].x, xs[c][3].x)) * mm; // pix A ch23
                half2v pb0 = u2h(pkrtz_u(xs[c][0].y, xs[c][1].y)) * mm; // pix B ch01
                half2v pb1 = u2h(pkrtz_u(xs[c][2].y, xs[c][3].y)) * mm; // pix B ch23
                u32x4 r;
                r.x = h2u(pa0); r.y = h2u(pa1); r.z = h2u(pb0); r.w = h2u(pb1);
                *(u32x4*)&dst[pidx] = r;            // ds_write_b128 (16B aligned)
            }
        }
    };

    // ---- prologue: stage c4=0 into tile[0] ----
    STAGE_LOAD(0);
    STAGE_WRITE(tile[0]);

    const int in1off = (h0 + ty) * W_ + tx;
    float a0 = in1g[in1off], a1 = in1g[in1off + HW_];
    float a2 = in1g[in1off + 2 * HW_], a3 = in1g[in1off + 3 * HW_];

    const int lbase = ty * TCOLS + tx;

#pragma unroll
    for (int c4 = 0; c4 < NC4; ++c4) {
        const bool more = (c4 + 1 < NC4);

        if (more) STAGE_LOAD(c4 + 1);   // issue loads before the barrier

        __syncthreads();                // tile[c4&1] ready; readers done w/ other buf

        if (more) STAGE_WRITE(tile[(c4 + 1) & 1]);

        const u32x2* lt = tile[c4 & 1]; // compile-time after unroll
        half2v ha = pkrtz(a0, a1);
        half2v hb = pkrtz(a2, a3);
        if (more) {                     // prefetch next in1 quad
            const float* p = in1g + (size_t)(4 * (c4 + 1)) * HW_ + in1off;
            a0 = p[0]; a1 = p[HW_]; a2 = p[2 * HW_]; a3 = p[3 * HW_];
        }

        const u32x2* wrow = PACKED ? (wp + ((size_t)g * NC4 + c4) * NO + pass * NDY * F_) : nullptr;
        const float* wr = wraw + (size_t)(g * CG + 4 * c4) * NO + pass * NDY * F_;

#pragma unroll
        for (int dyp = 0; dyp < NDY; ++dyp) {
#pragma unroll
            for (int dx = 0; dx < F_; ++dx) {
                const int oo = dyp * F_ + dx;
                u32x2 uv = lt[lbase + dyp * 2 * TCOLS + dx * 2]; // ds_read_b64, imm offset
                half2v wa, wb;
                if (PACKED) {
                    u32x2 wv = wrow[oo];            // wave-uniform -> s_load
                    wa = u2h(wv.x); wb = u2h(wv.y);
                } else {
                    wa = pkrtz(wr[oo], wr[oo + NO]);
                    wb = pkrtz(wr[oo + 2 * NO], wr[oo + 3 * NO]);
                }
                half2v p0 = wa * ha;                // v_pk_mul_f16
                half2v p1 = wb * hb;
                float s = FDOT2(p0, u2h(uv.x), acc[oo]);
                acc[oo]  = FDOT2(p1, u2h(uv.y), s); // v_dot2_f32_f16 x2
            }
        }
    }

    // write this pass's 27 output planes: out[b][g*81 + pass*27 + oo][h][w]
    size_t obase = (((size_t)pair * NO + pass * NDY * F_) * H_ + (h0 + ty)) * W_ + tx;
#pragma unroll
    for (int oo = 0; oo < NDY * F_; ++oo)
        out[obase + (size_t)oo * HW_] = acc[oo];
}

extern "C" void kernel_launch(void* const* d_in, const int* in_sizes, int n_in,
                              void* d_out, int out_size, void* d_ws, size_t ws_size,
                              hipStream_t stream) {
    const float* in1  = (const float*)d_in[0];
    const float* in2  = (const float*)d_in[1];
    const float* wraw = (const float*)d_in[2];
    float* out = (float*)d_out;

    const size_t wp_bytes = (size_t)G_ * NC4 * NO * 8;  // 41,472 B
    const int nblocks = 16 * 3 * (H_ / TH);             // 2304

    if (ws_size >= wp_bytes) {
        u32x2* wp = (u32x2*)d_ws;
        int n = G_ * NC4 * NO;
        pack_weights_kernel<<<(n + 255) / 256, 256, 0, stream>>>(wraw, wp);
        wcorr_kernel<true><<<nblocks, 256, 0, stream>>>(in1, in2, wp, wraw, out);
    } else {
        wcorr_kernel<false><<<nblocks, 256, 0, stream>>>(in1, in2, nullptr, wraw, out);
    }
}

// Round 7
// 80.528 us; speedup vs baseline: 6.8552x; 6.8552x over previous
//
#include <hip/hip_runtime.h>

// Problem constants (fixed by setup_inputs)
#define B_   4
#define C_   256
#define H_   96
#define W_   128
#define F_   9
#define G_   4
#define CG   64            // channels per group
#define NC4  16            // channel QUADS per group
#define NO   81            // offsets
#define TH   2             // output rows per block
#define TCOLS (W_ + 16)    // 144 halo cols = 72 even + 72 odd
#define HCOL2 72
#define HW_  (H_ * W_)

// Per-pass geometry: 3 dy-values per pass (dy = pass*3 + dyp)
#define NDY   3
#define PROWS (2 * NDY)          // 6 tile rows per pass (dilation=2, TH=2)
#define PTE   (PROWS * TCOLS)    // 864 pixels, 8B each (4 ch f16)
#define PNK   4                  // ceil(864/256) staging chunks
#define TILE_E PTE               // entries per buffer

typedef _Float16 half2v __attribute__((ext_vector_type(2)));
typedef unsigned u32x2 __attribute__((ext_vector_type(2)));

__device__ __forceinline__ half2v u2h(unsigned u) {
    half2v h; __builtin_memcpy(&h, &u, 4); return h;
}
__device__ __forceinline__ unsigned h2u(half2v h) {
    unsigned u; __builtin_memcpy(&u, &h, 4); return u;
}
__device__ __forceinline__ half2v pkrtz(float a, float b) {
    auto r = __builtin_amdgcn_cvt_pkrtz(a, b);
    half2v h; __builtin_memcpy(&h, &r, 4); return h;
}
__device__ __forceinline__ unsigned pkrtz_u(float a, float b) {
    auto r = __builtin_amdgcn_cvt_pkrtz(a, b);
    unsigned u; __builtin_memcpy(&u, &r, 4); return u;
}

#if __has_builtin(__builtin_amdgcn_fdot2)
#define FDOT2(a, b, c) __builtin_amdgcn_fdot2((a), (b), (c), false)
#else
__device__ __forceinline__ float fdot2_fb(half2v a, half2v b, float c) {
    return c + (float)a[0] * (float)b[0] + (float)a[1] * (float)b[1];
}
#define FDOT2(a, b, c) fdot2_fb((a), (b), (c))
#endif

// Pack weights [C,9,9] f32 -> [g][c4][o] as 4-channel (2x f16x2) in d_ws
__global__ void pack_weights_kernel(const float* __restrict__ w,
                                    u32x2* __restrict__ wp) {
    int i = blockIdx.x * blockDim.x + threadIdx.x;
    if (i >= G_ * NC4 * NO) return;
    int o  = i % NO;
    int c4 = (i / NO) % NC4;
    int g  = i / (NO * NC4);
    const float* base = w + (size_t)(g * CG + 4 * c4) * NO + o;
    u32x2 r;
    r.x = pkrtz_u(base[0], base[NO]);
    r.y = pkrtz_u(base[2 * NO], base[3 * NO]);
    wp[i] = r;
}

template <bool PACKED>
__global__ __launch_bounds__(256)
void wcorr_kernel(const float* __restrict__ in1, const float* __restrict__ in2,
                  const u32x2* __restrict__ wp, const float* __restrict__ wraw,
                  float* __restrict__ out) {
    // parity-split: entry = (row*2 + (hcol&1))*HCOL2 + (hcol>>1)
    __shared__ u32x2 tile[2][TILE_E];   // 13,824 B

    // grid = 16 pairs x 3 passes x 48 hblks = 2304 blocks
    // XCD-aware: (b,g) pair constant per XCD run -> in2 plane stays in XCD L2
    int bid  = blockIdx.x;
    int xcd  = bid & 7;
    int slot = bid >> 3;                 // 0..287
    int pair = xcd + 8 * (slot / 144);   // 0..15  == b*4+g
    int rem  = slot % 144;
    int pass = rem / 48;                 // 0..2  (dy block)
    int hblk = rem % 48;
    int b = pair >> 2, g = pair & 3;
    int h0 = hblk * TH;

    int t  = threadIdx.x;
    int ty = t >> 7;                // 0..1
    int tx = t & 127;               // 0..127

    const float* in1g = in1 + (size_t)(b * C_ + g * CG) * HW_;
    const float* in2g = in2 + (size_t)(b * C_ + g * CG) * HW_;

    // ---- staging geometry (c4-invariant): clamp + mask, no branches ----
    const int gr0 = h0 - 8 + 6 * pass;
    int po[PNK];        // clamped element offset into the channel plane
    unsigned msk[PNK];  // f16x2 (m,m) zero-mask
    int lix[PNK];       // parity-split LDS entry index
#pragma unroll
    for (int k = 0; k < PNK; ++k) {
        int pidx = k * 256 + t;
        int row  = pidx / TCOLS;
        int hcol = pidx - row * TCOLS;
        int gr = gr0 + row, gc = hcol - 8;
        bool inb = (pidx < PTE) && gr >= 0 && gr < H_ && gc >= 0 && gc < W_;
        int off = gr * W_ + gc;
        off = off < 0 ? 0 : (off > HW_ - 1 ? HW_ - 1 : off);
        po[k]  = off;
        float m = inb ? 1.f : 0.f;
        msk[k] = pkrtz_u(m, m);
        lix[k] = (row * 2 + (hcol & 1)) * HCOL2 + (hcol >> 1);
    }

    float acc[NDY * F_];
#pragma unroll
    for (int o = 0; o < NDY * F_; ++o) acc[o] = 0.f;

    // ---- prologue: stage c4=0 into tile[0] ----
    {
#pragma unroll
        for (int k = 0; k < PNK; ++k) {
            float v0 = in2g[po[k]],           v1 = in2g[po[k] + HW_];
            float v2 = in2g[po[k] + 2 * HW_], v3 = in2g[po[k] + 3 * HW_];
            if (k < PNK - 1 || t < PTE - (PNK - 1) * 256) {
                half2v m = u2h(msk[k]);
                u32x2 r;
                r.x = h2u(u2h(pkrtz_u(v0, v1)) * m);
                r.y = h2u(u2h(pkrtz_u(v2, v3)) * m);
                tile[0][lix[k]] = r;
            }
        }
    }

    const int in1off = (h0 + ty) * W_ + tx;
    float a0 = in1g[in1off], a1 = in1g[in1off + HW_];
    float a2 = in1g[in1off + 2 * HW_], a3 = in1g[in1off + 3 * HW_];

    const int p     = tx & 1;        // parity of this thread's output col
    const int cbase = tx >> 1;       // col2 base (taps are cbase..cbase+8)

    for (int c4 = 0; c4 < NC4; ++c4) {
        const bool more = (c4 + 1 < NC4);

        // issue next tile's global loads BEFORE the barrier
        float v0[PNK], v1[PNK], v2[PNK], v3[PNK];
        if (more) {
            const float* chb = in2g + (size_t)(4 * (c4 + 1)) * HW_;
#pragma unroll
            for (int k = 0; k < PNK; ++k) {
                v0[k] = chb[po[k]];           v1[k] = chb[po[k] + HW_];
                v2[k] = chb[po[k] + 2 * HW_]; v3[k] = chb[po[k] + 3 * HW_];
            }
        }

        __syncthreads();   // tile[c4&1] ready; all readers done with other buf

        if (more) {
            u32x2* dst = tile[(c4 + 1) & 1];
#pragma unroll
            for (int k = 0; k < PNK; ++k) {
                if (k < PNK - 1 || t < PTE - (PNK - 1) * 256) {
                    half2v m = u2h(msk[k]);
                    u32x2 r;
                    r.x = h2u(u2h(pkrtz_u(v0[k], v1[k])) * m);
                    r.y = h2u(u2h(pkrtz_u(v2[k], v3[k])) * m);
                    dst[lix[k]] = r;
                }
            }
        }

        const u32x2* lt = tile[c4 & 1];
        half2v ha = pkrtz(a0, a1);
        half2v hb = pkrtz(a2, a3);
        if (more) {   // prefetch next in1 quad
            const float* pp = in1g + (size_t)(4 * (c4 + 1)) * HW_ + in1off;
            a0 = pp[0]; a1 = pp[HW_]; a2 = pp[2 * HW_]; a3 = pp[3 * HW_];
        }

        const u32x2* wrow = PACKED ? (wp + ((size_t)g * NC4 + c4) * NO + pass * NDY * F_) : nullptr;
        const float* wr = wraw + (size_t)(g * CG + 4 * c4) * NO + pass * NDY * F_;

#pragma unroll
        for (int dyp = 0; dyp < NDY; ++dyp) {
            // 9 consecutive 8B entries -> ds_read2_b64 pairs (compile-time offsets)
            const u32x2* eb = lt + ((2 * dyp + ty) * 2 + p) * HCOL2 + cbase;
            u32x2 e[9];
#pragma unroll
            for (int k = 0; k < 9; ++k) e[k] = eb[k];

#pragma unroll
            for (int dx = 0; dx < F_; ++dx) {
                const int oo = dyp * F_ + dx;
                half2v wa, wb;
                if (PACKED) {
                    u32x2 wv = wrow[oo];            // wave-uniform -> s_load
                    wa = u2h(wv.x); wb = u2h(wv.y);
                } else {
                    wa = pkrtz(wr[oo], wr[oo + NO]);
                    wb = pkrtz(wr[oo + 2 * NO], wr[oo + 3 * NO]);
                }
                half2v p0 = wa * ha;                // v_pk_mul_f16
                half2v p1 = wb * hb;
                float s = FDOT2(p0, u2h(e[dx].x), acc[oo]);
                acc[oo]  = FDOT2(p1, u2h(e[dx].y), s); // v_dot2_f32_f16 x2
            }
        }
    }

    // write this pass's 27 output planes: out[b][g*81 + pass*27 + oo][h][w]
    size_t obase = (((size_t)pair * NO + pass * NDY * F_) * H_ + (h0 + ty)) * W_ + tx;
#pragma unroll
    for (int oo = 0; oo < NDY * F_; ++oo)
        out[obase + (size_t)oo * HW_] = acc[oo];
}

extern "C" void kernel_launch(void* const* d_in, const int* in_sizes, int n_in,
                              void* d_out, int out_size, void* d_ws, size_t ws_size,
                              hipStream_t stream) {
    const float* in1  = (const float*)d_in[0];
    const float* in2  = (const float*)d_in[1];
    const float* wraw = (const float*)d_in[2];
    float* out = (float*)d_out;

    const size_t wp_bytes = (size_t)G_ * NC4 * NO * 8;  // 41,472 B
    const int nblocks = 16 * 3 * (H_ / TH);             // 2304

    if (ws_size >= wp_bytes) {
        u32x2* wp = (u32x2*)d_ws;
        int n = G_ * NC4 * NO;
        pack_weights_kernel<<<(n + 255) / 256, 256, 0, stream>>>(wraw, wp);
        wcorr_kernel<true><<<nblocks, 256, 0, stream>>>(in1, in2, wp, wraw, out);
    } else {
        wcorr_kernel<false><<<nblocks, 256, 0, stream>>>(in1, in2, nullptr, wraw, out);
    }
}